// Round 5
// baseline (1183.373 us; speedup 1.0000x reference)
//
#include <hip/hip_runtime.h>

#define NN    60000
#define NODES 100000
#define DD    64
#define NNZ   3200000
#define BB    1024
#define NEG   0.2f
#define RPB   256                        // rows per bucket
#define NBUCK 391                        // ceil(NODES/RPB)
#define EPB   8192                       // edges per sort block
#define NPB   ((NNZ + EPB - 1) / EPB)    // 391
#define CAP   8960                       // fixed bucket capacity (mean 8184, sd~90)
#define BCAP  9216                       // LDS edge capacity in k_csr
#define XS    (NODES * 8)                // floats per feature shard (3.2 MB)

// ---------------------------------------------------------------- init x (sharded layout)
__global__ __launch_bounds__(256) void k_init_x(const float* __restrict__ eu,
                                                const float* __restrict__ ei,
                                                float* __restrict__ x) {
    int i = blockIdx.x * 256 + threadIdx.x;          // float4 index over input
    const int TOT = NODES * DD / 4;
    if (i >= TOT) return;
    const int UE = NN * DD / 4;
    float4 v = (i < UE) ? ((const float4*)eu)[i] : ((const float4*)ei)[i - UE];
    int n = i >> 4, c4 = i & 15;
    int s8 = c4 >> 1, half = c4 & 1;
    ((float4*)x)[s8 * (XS / 4) + n * 2 + half] = v;
}

// ---------------------------------------------------------------- init gcur[b] = b*CAP
__global__ __launch_bounds__(512) void k_initg(int* __restrict__ gcur) {
    int t = threadIdx.x;
    if (t < NBUCK) gcur[t] = t * CAP;
}

// ---------------------------------------------------------------- bucket sort -> bulk
__global__ __launch_bounds__(512) void k_place(const int* __restrict__ row,
                                               const int* __restrict__ col,
                                               const float* __restrict__ val,
                                               int* __restrict__ gcur,
                                               int2* __restrict__ bulk) {
    __shared__ int rows_l[EPB];                // 32 KB
    __shared__ unsigned short perm[EPB];       // 16 KB
    __shared__ int h[NBUCK], bloc[NBUCK], bcur[NBUCK], gseg[NBUCK];
    __shared__ int sc[512];
    int t = threadIdx.x;
    if (t < NBUCK) h[t] = 0;
    __syncthreads();
    int base = blockIdx.x * EPB;
    int n = min(EPB, NNZ - base);
    for (int k = t; k < n; k += 512) {
        int r = row[base + k];
        rows_l[k] = r;
        atomicAdd(&h[r >> 8], 1);
    }
    __syncthreads();
    {
        int v = (t < NBUCK) ? h[t] : 0;
        sc[t] = v;
        __syncthreads();
        for (int off = 1; off < 512; off <<= 1) {
            int u = (t >= off) ? sc[t - off] : 0;
            __syncthreads();
            sc[t] += u;
            __syncthreads();
        }
        if (t < NBUCK) {
            int ex = sc[t] - v;
            bloc[t] = ex;
            bcur[t] = ex;
            gseg[t] = v ? atomicAdd(&gcur[t], v) : 0;
        }
    }
    __syncthreads();
    for (int k = t; k < n; k += 512) {
        int p = atomicAdd(&bcur[rows_l[k] >> 8], 1);
        perm[p] = (unsigned short)k;
    }
    __syncthreads();
    for (int j = t; j < n; j += 512) {
        int k = perm[j];
        int r = rows_l[k];
        int b8 = r >> 8;
        int addr = gseg[b8] + (j - bloc[b8]);
        bulk[addr] = make_int2(((r & 255) << 17) | col[base + k],
                               __float_as_int(val[base + k]));
    }
}

// ---------------------------------------------------------------- per-bucket row sort (in place)
__global__ __launch_bounds__(512) void k_csr(const int* __restrict__ gcur,
                                             int2* __restrict__ bulk,
                                             int2* __restrict__ rsd) {
    __shared__ int2 eds[BCAP];                 // 72 KB
    __shared__ int h[RPB], sc[RPB], bcur[RPB];
    int b = blockIdx.x, t = threadIdx.x;
    int lo = b * CAP;
    int n = gcur[b] - lo;
    if (t < RPB) h[t] = 0;
    __syncthreads();
    for (int i = t; i < n; i += 512) {
        int2 ed = bulk[lo + i];
        eds[i] = ed;
        atomicAdd(&h[ed.x >> 17], 1);
    }
    __syncthreads();
    int v = 0;
    if (t < RPB) { v = h[t]; sc[t] = v; }
    __syncthreads();
    for (int off = 1; off < RPB; off <<= 1) {
        int u = 0;
        if (t < RPB && t >= off) u = sc[t - off];
        __syncthreads();
        if (t < RPB) sc[t] += u;
        __syncthreads();
    }
    if (t < RPB) {
        int ex = sc[t] - v;
        bcur[t] = ex;
        int r = b * RPB + t;
        if (r < NODES) rsd[r] = make_int2(lo + ex, lo + ex + v);
    }
    __syncthreads();
    for (int i = t; i < n; i += 512) {
        int2 ed = eds[i];
        int p = atomicAdd(&bcur[ed.x >> 17], 1);
        bulk[lo + p] = make_int2(ed.x & 0x1FFFF, ed.y);
    }
}

// ---------------------------------------------------------------- feature-sharded pull SpMM
// shard s = blockIdx&7 (XCD-pinned); wave = 1 row: lane = 8*edge_slot + dim,
// 32B L2-resident gathers, butterfly-reduce over edge axis.
__global__ __launch_bounds__(256) void k_spmm(const int2* __restrict__ rsd,
                                              const int2* __restrict__ cv,
                                              const float* __restrict__ xs,
                                              float* __restrict__ lies) {
    int s    = blockIdx.x & 7;
    int rblk = blockIdx.x >> 3;
    int wid  = threadIdx.x >> 6, lane = threadIdx.x & 63;
    int row  = rblk * 4 + wid;
    if (row >= NODES) return;
    int esub = lane >> 3, d = lane & 7;
    int2 se = rsd[row];
    const float* xb = xs + s * XS + d;
    float acc = 0.f;
    for (int base = se.x; base < se.y; base += 16) {
        int g0 = base + esub, g1 = base + 8 + esub;
        int2 e0 = (g0 < se.y) ? cv[g0] : make_int2(0, 0);
        int2 e1 = (g1 < se.y) ? cv[g1] : make_int2(0, 0);
        float x0 = xb[e0.x * 8];
        float x1 = xb[e1.x * 8];
        acc = fmaf(__int_as_float(e0.y), x0, acc);
        acc = fmaf(__int_as_float(e1.y), x1, acc);
    }
    acc += __shfl_xor(acc, 8);
    acc += __shfl_xor(acc, 16);
    acc += __shfl_xor(acc, 32);
    if (esub == 0) lies[s * XS + row * 8 + d] = acc;
}

// ---------------------------------------------------------------- fused layer GEMM (sharded x/lie)
__global__ __launch_bounds__(256) void k_gemm(float* __restrict__ x,
                                              const float* __restrict__ lie,
                                              const float* __restrict__ W1,
                                              const float* __restrict__ W2,
                                              const float* __restrict__ b1,
                                              const float* __restrict__ b2) {
    __shared__ float A1[64 * 64];
    __shared__ float A2[64 * 64];
    __shared__ float Ws1[64 * 64];
    __shared__ float Ws2[64 * 64];

    const int t = threadIdx.x;
    const int row0 = blockIdx.x * 64;

    {
        const float4* w1v = (const float4*)W1;
        const float4* w2v = (const float4*)W2;
        float4* s1v = (float4*)Ws1;
        float4* s2v = (float4*)Ws2;
#pragma unroll
        for (int q = 0; q < 4; ++q) {
            s1v[q * 256 + t] = w1v[q * 256 + t];
            s2v[q * 256 + t] = w2v[q * 256 + t];
        }
    }
#pragma unroll
    for (int q = 0; q < 4; ++q) {
        int f4 = q * 256 + t;
        int rl = f4 >> 4;
        int c4 = f4 & 15;
        int gr = row0 + rl;
        float4 lv = make_float4(0.f, 0.f, 0.f, 0.f);
        float4 xv = make_float4(0.f, 0.f, 0.f, 0.f);
        if (gr < NODES) {
            int a4 = (c4 >> 1) * (XS / 4) + gr * 2 + (c4 & 1);
            lv = ((const float4*)lie)[a4];
            xv = ((const float4*)x)[a4];
        }
        int sg = c4 ^ (rl & 15);
        ((float4*)A1)[rl * 16 + sg] = lv;
        ((float4*)A2)[rl * 16 + sg] = make_float4(lv.x * xv.x, lv.y * xv.y,
                                                  lv.z * xv.z, lv.w * xv.w);
    }
    __syncthreads();

    const int tx = t & 15;
    const int ty = t >> 4;
    float bs[4];
    {
        float4 bb1 = *(const float4*)&b1[tx * 4];
        float4 bb2 = *(const float4*)&b2[tx * 4];
        bs[0] = bb1.x + bb2.x; bs[1] = bb1.y + bb2.y;
        bs[2] = bb1.z + bb2.z; bs[3] = bb1.w + bb2.w;
    }
    float acc[4][4];
#pragma unroll
    for (int i = 0; i < 4; ++i)
#pragma unroll
        for (int j = 0; j < 4; ++j) acc[i][j] = bs[j];

    for (int k4 = 0; k4 < 16; ++k4) {
        float4 a1[4], a2[4];
#pragma unroll
        for (int i = 0; i < 4; ++i) {
            int r = ty * 4 + i;
            int sg = k4 ^ (r & 15);
            a1[i] = ((const float4*)A1)[r * 16 + sg];
            a2[i] = ((const float4*)A2)[r * 16 + sg];
        }
#pragma unroll
        for (int kk = 0; kk < 4; ++kk) {
            float4 w1 = ((const float4*)Ws1)[(k4 * 4 + kk) * 16 + tx];
            float4 w2 = ((const float4*)Ws2)[(k4 * 4 + kk) * 16 + tx];
#pragma unroll
            for (int i = 0; i < 4; ++i) {
                float av1 = (&a1[i].x)[kk];
                float av2 = (&a2[i].x)[kk];
                acc[i][0] = fmaf(av1, w1.x, fmaf(av2, w2.x, acc[i][0]));
                acc[i][1] = fmaf(av1, w1.y, fmaf(av2, w2.y, acc[i][1]));
                acc[i][2] = fmaf(av1, w1.z, fmaf(av2, w2.z, acc[i][2]));
                acc[i][3] = fmaf(av1, w1.w, fmaf(av2, w2.w, acc[i][3]));
            }
        }
    }
#pragma unroll
    for (int i = 0; i < 4; ++i) {
        int gr = row0 + ty * 4 + i;
        if (gr < NODES) {
            float4 o;
            o.x = acc[i][0] >= 0.f ? acc[i][0] : NEG * acc[i][0];
            o.y = acc[i][1] >= 0.f ? acc[i][1] : NEG * acc[i][1];
            o.z = acc[i][2] >= 0.f ? acc[i][2] : NEG * acc[i][2];
            o.w = acc[i][3] >= 0.f ? acc[i][3] : NEG * acc[i][3];
            ((float4*)x)[(tx >> 1) * (XS / 4) + gr * 2 + (tx & 1)] = o;
        }
    }
}

// ---------------------------------------------------------------- gather layer repr into output
__global__ __launch_bounds__(256) void k_gather(const float* __restrict__ x,
                                                const int* __restrict__ su,
                                                const int* __restrict__ oi,
                                                const int* __restrict__ ui,
                                                float* __restrict__ out, int layer) {
    int w    = (blockIdx.x * 256 + threadIdx.x) >> 6;
    int lane = threadIdx.x & 63;
    if (w >= 3 * BB) return;
    int g = w >> 10, b = w & 1023;
    int node = (g == 0) ? su[b] : (NN + ((g == 1) ? oi[b] : ui[b]));
    out[w * 256 + layer * 64 + lane] = x[(lane >> 3) * XS + node * 8 + (lane & 7)];
}

// ---------------------------------------------------------------- launch
extern "C" void kernel_launch(void* const* d_in, const int* in_sizes, int n_in,
                              void* d_out, int out_size, void* d_ws, size_t ws_size,
                              hipStream_t stream) {
    const int*   edge_row = (const int*)d_in[0];
    const int*   edge_col = (const int*)d_in[1];
    const float* edge_val = (const float*)d_in[2];
    const float* eu = (const float*)d_in[3];
    const float* ei = (const float*)d_in[4];
    const float* W1 = (const float*)d_in[5];
    const float* W2 = (const float*)d_in[6];
    const float* b1 = (const float*)d_in[7];
    const float* b2 = (const float*)d_in[8];
    const int*   su = (const int*)d_in[9];
    const int*   oi = (const int*)d_in[10];
    const int*   ui = (const int*)d_in[11];
    float* out = (float*)d_out;

    // workspace carve (~80 MB)
    float* x    = (float*)d_ws;                    // 6.4M f (sharded)
    float* lie  = x + NODES * DD;                  // 6.4M f (sharded)
    int2*  bulk = (int2*)(lie + NODES * DD);       // NBUCK*CAP int2 (28 MB)
    int*   gcur = (int*)(bulk + NBUCK * CAP);      // NBUCK
    int2*  rsd  = (int2*)(gcur + NBUCK + 1);       // NODES int2 (800 KB)

    k_initg<<<1, 512, 0, stream>>>(gcur);
    k_init_x<<<(NODES * DD / 4 + 255) / 256, 256, 0, stream>>>(eu, ei, x);
    k_gather<<<(3 * BB * 64 + 255) / 256, 256, 0, stream>>>(x, su, oi, ui, out, 0);

    k_place<<<NPB, 512, 0, stream>>>(edge_row, edge_col, edge_val, gcur, bulk);
    k_csr<<<NBUCK, 512, 0, stream>>>(gcur, bulk, rsd);

    for (int l = 0; l < 3; ++l) {
        k_spmm<<<8 * ((NODES + 3) / 4), 256, 0, stream>>>(rsd, bulk, x, lie);
        k_gemm<<<(NODES + 63) / 64, 256, 0, stream>>>(x, lie,
                                                      W1 + l * 4096, W2 + l * 4096,
                                                      b1 + l * 64,  b2 + l * 64);
        k_gather<<<(3 * BB * 64 + 255) / 256, 256, 0, stream>>>(x, su, oi, ui, out, l + 1);
    }
}

// Round 6
// 610.724 us; speedup vs baseline: 1.9377x; 1.9377x over previous
//
#include <hip/hip_runtime.h>

#define NN    60000
#define NODES 100000
#define DD    64
#define NNZ   3200000
#define BB    1024
#define NEG   0.2f
#define RPB   256                        // rows per bucket
#define NBUCK 391                        // ceil(NODES/RPB)
#define EPB   8192                       // edges per sort block
#define NPB   ((NNZ + EPB - 1) / EPB)    // 391
#define CAP   8960                       // fixed bucket capacity (mean 8184, sd~90)
#define BCAP  9216                       // LDS edge capacity in k_csr

// ---------------------------------------------------------------- init x = concat(eu, ei); also init gcur
__global__ __launch_bounds__(256) void k_init_x(const float* __restrict__ eu,
                                                const float* __restrict__ ei,
                                                float* __restrict__ x,
                                                int* __restrict__ gcur) {
    int i = blockIdx.x * 256 + threadIdx.x;          // float4 index
    if (i < NBUCK) gcur[i] = i * CAP;
    const int TOT = NODES * DD / 4;
    if (i >= TOT) return;
    const int UE = NN * DD / 4;
    float4 v = (i < UE) ? ((const float4*)eu)[i] : ((const float4*)ei)[i - UE];
    ((float4*)x)[i] = v;
}

// ---------------------------------------------------------------- bucket sort -> bulk
// block-local LDS counting sort -> contiguous ascending global write runs
__global__ __launch_bounds__(512) void k_place(const int* __restrict__ row,
                                               const int* __restrict__ col,
                                               const float* __restrict__ val,
                                               int* __restrict__ gcur,
                                               int2* __restrict__ bulk) {
    __shared__ int rows_l[EPB];                // 32 KB
    __shared__ unsigned short perm[EPB];       // 16 KB
    __shared__ int h[NBUCK], bloc[NBUCK], bcur[NBUCK], gseg[NBUCK];
    __shared__ int sc[512];
    int t = threadIdx.x;
    if (t < NBUCK) h[t] = 0;
    __syncthreads();
    int base = blockIdx.x * EPB;
    int n = min(EPB, NNZ - base);
    for (int k = t; k < n; k += 512) {
        int r = row[base + k];
        rows_l[k] = r;
        atomicAdd(&h[r >> 8], 1);
    }
    __syncthreads();
    {
        int v = (t < NBUCK) ? h[t] : 0;
        sc[t] = v;
        __syncthreads();
        for (int off = 1; off < 512; off <<= 1) {
            int u = (t >= off) ? sc[t - off] : 0;
            __syncthreads();
            sc[t] += u;
            __syncthreads();
        }
        if (t < NBUCK) {
            int ex = sc[t] - v;
            bloc[t] = ex;
            bcur[t] = ex;
            gseg[t] = v ? atomicAdd(&gcur[t], v) : 0;
        }
    }
    __syncthreads();
    for (int k = t; k < n; k += 512) {
        int p = atomicAdd(&bcur[rows_l[k] >> 8], 1);
        perm[p] = (unsigned short)k;
    }
    __syncthreads();
    for (int j = t; j < n; j += 512) {
        int k = perm[j];
        int r = rows_l[k];
        int b8 = r >> 8;
        int addr = gseg[b8] + (j - bloc[b8]);
        bulk[addr] = make_int2(((r & 255) << 17) | col[base + k],
                               __float_as_int(val[base + k]));
    }
}

// ---------------------------------------------------------------- per-bucket row sort (in place)
__global__ __launch_bounds__(512) void k_csr(const int* __restrict__ gcur,
                                             int2* __restrict__ bulk,
                                             int2* __restrict__ rsd) {
    __shared__ int2 eds[BCAP];                 // 72 KB
    __shared__ int h[RPB], sc[RPB], bcur[RPB];
    int b = blockIdx.x, t = threadIdx.x;
    int lo = b * CAP;
    int n = gcur[b] - lo;
    if (t < RPB) h[t] = 0;
    __syncthreads();
    for (int i = t; i < n; i += 512) {
        int2 ed = bulk[lo + i];
        eds[i] = ed;
        atomicAdd(&h[ed.x >> 17], 1);
    }
    __syncthreads();
    int v = 0;
    if (t < RPB) { v = h[t]; sc[t] = v; }
    __syncthreads();
    for (int off = 1; off < RPB; off <<= 1) {
        int u = 0;
        if (t < RPB && t >= off) u = sc[t - off];
        __syncthreads();
        if (t < RPB) sc[t] += u;
        __syncthreads();
    }
    if (t < RPB) {
        int ex = sc[t] - v;
        bcur[t] = ex;
        int r = b * RPB + t;
        if (r < NODES) rsd[r] = make_int2(lo + ex, lo + ex + v);
    }
    __syncthreads();
    for (int i = t; i < n; i += 512) {
        int2 ed = eds[i];
        int p = atomicAdd(&bcur[ed.x >> 17], 1);
        bulk[lo + p] = make_int2(ed.x & 0x1FFFF, ed.y);
    }
}

// ---------------------------------------------------------------- pull SpMM: one wave / row,
// broadcast cv loads (no shuffles), 16 gathers in flight
__global__ __launch_bounds__(256) void k_spmm(const int2* __restrict__ rsd,
                                              const int2* __restrict__ cv,
                                              const float* __restrict__ x,
                                              float* __restrict__ lie) {
    int w    = (blockIdx.x * 256 + threadIdx.x) >> 6;
    int lane = threadIdx.x & 63;
    if (w >= NODES) return;
    int2 se = rsd[w];
    int s = se.x, e = se.y;
    float acc = 0.f;
    int g = s;
    for (; g + 16 <= e; g += 16) {
        int2 ee[16];
#pragma unroll
        for (int j = 0; j < 16; ++j) ee[j] = cv[g + j];
        float xv[16];
#pragma unroll
        for (int j = 0; j < 16; ++j) xv[j] = x[ee[j].x * DD + lane];
#pragma unroll
        for (int j = 0; j < 16; ++j) acc = fmaf(__int_as_float(ee[j].y), xv[j], acc);
    }
    for (; g + 8 <= e; g += 8) {
        int2 ee[8];
#pragma unroll
        for (int j = 0; j < 8; ++j) ee[j] = cv[g + j];
        float xv[8];
#pragma unroll
        for (int j = 0; j < 8; ++j) xv[j] = x[ee[j].x * DD + lane];
#pragma unroll
        for (int j = 0; j < 8; ++j) acc = fmaf(__int_as_float(ee[j].y), xv[j], acc);
    }
    for (; g < e; ++g) {
        int2 ed = cv[g];
        acc = fmaf(__int_as_float(ed.y), x[ed.x * DD + lane], acc);
    }
    lie[w * DD + lane] = acc;
}

// ---------------------------------------------------------------- fused layer GEMM
__global__ __launch_bounds__(256) void k_gemm(float* __restrict__ x,
                                              const float* __restrict__ lie,
                                              const float* __restrict__ W1,
                                              const float* __restrict__ W2,
                                              const float* __restrict__ b1,
                                              const float* __restrict__ b2) {
    __shared__ float A1[64 * 64];
    __shared__ float A2[64 * 64];
    __shared__ float Ws1[64 * 64];
    __shared__ float Ws2[64 * 64];

    const int t = threadIdx.x;
    const int row0 = blockIdx.x * 64;

    {
        const float4* w1v = (const float4*)W1;
        const float4* w2v = (const float4*)W2;
        float4* s1v = (float4*)Ws1;
        float4* s2v = (float4*)Ws2;
#pragma unroll
        for (int q = 0; q < 4; ++q) {
            s1v[q * 256 + t] = w1v[q * 256 + t];
            s2v[q * 256 + t] = w2v[q * 256 + t];
        }
    }
#pragma unroll
    for (int q = 0; q < 4; ++q) {
        int f4 = q * 256 + t;
        int rl = f4 >> 4;
        int c4 = f4 & 15;
        int gr = row0 + rl;
        float4 lv = make_float4(0.f, 0.f, 0.f, 0.f);
        float4 xv = make_float4(0.f, 0.f, 0.f, 0.f);
        if (gr < NODES) {
            lv = *(const float4*)&lie[gr * DD + c4 * 4];
            xv = *(const float4*)&x[gr * DD + c4 * 4];
        }
        int sg = c4 ^ (rl & 15);
        ((float4*)A1)[rl * 16 + sg] = lv;
        ((float4*)A2)[rl * 16 + sg] = make_float4(lv.x * xv.x, lv.y * xv.y,
                                                  lv.z * xv.z, lv.w * xv.w);
    }
    __syncthreads();

    const int tx = t & 15;
    const int ty = t >> 4;
    float bs[4];
    {
        float4 bb1 = *(const float4*)&b1[tx * 4];
        float4 bb2 = *(const float4*)&b2[tx * 4];
        bs[0] = bb1.x + bb2.x; bs[1] = bb1.y + bb2.y;
        bs[2] = bb1.z + bb2.z; bs[3] = bb1.w + bb2.w;
    }
    float acc[4][4];
#pragma unroll
    for (int i = 0; i < 4; ++i)
#pragma unroll
        for (int j = 0; j < 4; ++j) acc[i][j] = bs[j];

    for (int k4 = 0; k4 < 16; ++k4) {
        float4 a1[4], a2[4];
#pragma unroll
        for (int i = 0; i < 4; ++i) {
            int r = ty * 4 + i;
            int sg = k4 ^ (r & 15);
            a1[i] = ((const float4*)A1)[r * 16 + sg];
            a2[i] = ((const float4*)A2)[r * 16 + sg];
        }
#pragma unroll
        for (int kk = 0; kk < 4; ++kk) {
            float4 w1 = ((const float4*)Ws1)[(k4 * 4 + kk) * 16 + tx];
            float4 w2 = ((const float4*)Ws2)[(k4 * 4 + kk) * 16 + tx];
#pragma unroll
            for (int i = 0; i < 4; ++i) {
                float av1 = (&a1[i].x)[kk];
                float av2 = (&a2[i].x)[kk];
                acc[i][0] = fmaf(av1, w1.x, fmaf(av2, w2.x, acc[i][0]));
                acc[i][1] = fmaf(av1, w1.y, fmaf(av2, w2.y, acc[i][1]));
                acc[i][2] = fmaf(av1, w1.z, fmaf(av2, w2.z, acc[i][2]));
                acc[i][3] = fmaf(av1, w1.w, fmaf(av2, w2.w, acc[i][3]));
            }
        }
    }
#pragma unroll
    for (int i = 0; i < 4; ++i) {
        int gr = row0 + ty * 4 + i;
        if (gr < NODES) {
            float4 o;
            o.x = acc[i][0] >= 0.f ? acc[i][0] : NEG * acc[i][0];
            o.y = acc[i][1] >= 0.f ? acc[i][1] : NEG * acc[i][1];
            o.z = acc[i][2] >= 0.f ? acc[i][2] : NEG * acc[i][2];
            o.w = acc[i][3] >= 0.f ? acc[i][3] : NEG * acc[i][3];
            *(float4*)&x[gr * DD + tx * 4] = o;
        }
    }
}

// ---------------------------------------------------------------- gather layer repr into output
__global__ __launch_bounds__(256) void k_gather(const float* __restrict__ x,
                                                const int* __restrict__ su,
                                                const int* __restrict__ oi,
                                                const int* __restrict__ ui,
                                                float* __restrict__ out, int layer) {
    int w    = (blockIdx.x * 256 + threadIdx.x) >> 6;
    int lane = threadIdx.x & 63;
    if (w >= 3 * BB) return;
    int g = w >> 10, b = w & 1023;
    int node = (g == 0) ? su[b] : (NN + ((g == 1) ? oi[b] : ui[b]));
    out[w * 256 + layer * 64 + lane] = x[node * DD + lane];
}

// ---------------------------------------------------------------- launch
extern "C" void kernel_launch(void* const* d_in, const int* in_sizes, int n_in,
                              void* d_out, int out_size, void* d_ws, size_t ws_size,
                              hipStream_t stream) {
    const int*   edge_row = (const int*)d_in[0];
    const int*   edge_col = (const int*)d_in[1];
    const float* edge_val = (const float*)d_in[2];
    const float* eu = (const float*)d_in[3];
    const float* ei = (const float*)d_in[4];
    const float* W1 = (const float*)d_in[5];
    const float* W2 = (const float*)d_in[6];
    const float* b1 = (const float*)d_in[7];
    const float* b2 = (const float*)d_in[8];
    const int*   su = (const int*)d_in[9];
    const int*   oi = (const int*)d_in[10];
    const int*   ui = (const int*)d_in[11];
    float* out = (float*)d_out;

    // workspace carve (~80 MB)
    float* x    = (float*)d_ws;                    // 6.4M f
    float* lie  = x + NODES * DD;                  // 6.4M f
    int2*  bulk = (int2*)(lie + NODES * DD);       // NBUCK*CAP int2 (28 MB)
    int*   gcur = (int*)(bulk + NBUCK * CAP);      // NBUCK
    int2*  rsd  = (int2*)(gcur + NBUCK + 1);       // NODES int2 (800 KB)

    k_init_x<<<(NODES * DD / 4 + 255) / 256, 256, 0, stream>>>(eu, ei, x, gcur);
    k_gather<<<(3 * BB * 64 + 255) / 256, 256, 0, stream>>>(x, su, oi, ui, out, 0);

    k_place<<<NPB, 512, 0, stream>>>(edge_row, edge_col, edge_val, gcur, bulk);
    k_csr<<<NBUCK, 512, 0, stream>>>(gcur, bulk, rsd);

    for (int l = 0; l < 3; ++l) {
        k_spmm<<<(NODES * 64 + 255) / 256, 256, 0, stream>>>(rsd, bulk, x, lie);
        k_gemm<<<(NODES + 63) / 64, 256, 0, stream>>>(x, lie,
                                                      W1 + l * 4096, W2 + l * 4096,
                                                      b1 + l * 64,  b2 + l * 64);
        k_gather<<<(3 * BB * 64 + 255) / 256, 256, 0, stream>>>(x, su, oi, ui, out, l + 1);
    }
}